// Round 1
// baseline (297.645 us; speedup 1.0000x reference)
//
#include <hip/hip_runtime.h>
#include <hip/hip_bf16.h>

#define HC 60
#define WCC 60
#define DD 64
#define NCELL (HC * WCC)      // 3600
#define IMG (HC * 8)          // 480

typedef __bf16 bf16x8 __attribute__((ext_vector_type(8)));
typedef float f32x4 __attribute__((ext_vector_type(4)));

__device__ inline unsigned short f2bf(float f) {
    union { float f; unsigned u; } x; x.f = f;
    unsigned u = x.u;
    unsigned r = (u + 0x7fffu + ((u >> 16) & 1u)) >> 16;  // round-to-nearest-even
    return (unsigned short)r;
}

// ---- kernel 0: zero the two accumulators in workspace ----
__global__ void dl_init_kernel(float* wsf) {
    if (threadIdx.x < 2) wsf[threadIdx.x] = 0.f;
}

// ---- kernel 1: vm[b,k,l] = prod over 8x8 block of valid_mask; also sum(vm) ----
__global__ __launch_bounds__(256) void dl_vm_kernel(const float* __restrict__ mask,
                                                    float* __restrict__ vm,
                                                    float* __restrict__ vmsum) {
    int tid = threadIdx.x;
    int lane = tid & 63;
    int wv = tid >> 6;
    int cell = blockIdx.x * 4 + wv;            // 0 .. 14399
    int b = cell / NCELL;
    int rem = cell % NCELL;
    int k = rem / WCC, l = rem % WCC;
    int dy = lane >> 3, dx = lane & 7;
    float v = mask[(size_t)b * IMG * IMG + (size_t)(k * 8 + dy) * IMG + (l * 8 + dx)];
#pragma unroll
    for (int off = 32; off > 0; off >>= 1) v *= __shfl_xor(v, off);
    if (lane == 0) {
        vm[cell] = v;
        atomicAdd(vmsum, v);
    }
}

// ---- kernel 2: dense fused GEMM + sum(vm[kl]*max(0, dot-0.2)) ----
__global__ __launch_bounds__(256) void dl_gemm_loss_kernel(
    const float* __restrict__ desc, const float* __restrict__ wdesc,
    const float* __restrict__ vm, float* __restrict__ accum)
{
    __shared__ unsigned char sA[128 * 128];   // 128 rows x 64 bf16 (128B), XOR-swizzled
    __shared__ unsigned char sB[128 * 128];
    __shared__ float swave[4];

    const int b = blockIdx.z;
    const int m0 = blockIdx.x * 128;
    const int n0 = blockIdx.y * 128;
    const int tid = threadIdx.x;
    const int lane = tid & 63;
    const int wv = tid >> 6;

    const float* gA = desc + (size_t)b * NCELL * DD;
    const float* gB = wdesc + (size_t)b * NCELL * DD;

    // stage A and B tiles: f32 global -> bf16 LDS, zero-pad OOB rows (exact: dot=0 -> loss term 0)
#pragma unroll
    for (int pass = 0; pass < 8; ++pass) {
        int row = pass * 16 + (tid >> 4);       // 0..127
        int c4 = (tid & 15) * 4;                // f32 column
        int cb = (c4 * 2) ^ ((row & 7) << 4);   // swizzled byte offset
        {
            int gr = m0 + row;
            float4 v = make_float4(0.f, 0.f, 0.f, 0.f);
            if (gr < NCELL) v = *(const float4*)(gA + (size_t)gr * DD + c4);
            ushort4 p;
            p.x = f2bf(v.x); p.y = f2bf(v.y); p.z = f2bf(v.z); p.w = f2bf(v.w);
            *(ushort4*)(sA + row * 128 + cb) = p;
        }
        {
            int gr = n0 + row;
            float4 v = make_float4(0.f, 0.f, 0.f, 0.f);
            if (gr < NCELL) v = *(const float4*)(gB + (size_t)gr * DD + c4);
            ushort4 p;
            p.x = f2bf(v.x); p.y = f2bf(v.y); p.z = f2bf(v.z); p.w = f2bf(v.w);
            *(ushort4*)(sB + row * 128 + cb) = p;
        }
    }
    __syncthreads();

    const int wr = wv >> 1, wcol = wv & 1;      // wave -> 64x64 subtile
    f32x4 acc[4][4];
#pragma unroll
    for (int i2 = 0; i2 < 4; ++i2)
#pragma unroll
        for (int j2 = 0; j2 < 4; ++j2)
            acc[i2][j2] = (f32x4)(0.f);

    const int kgrp = (lane >> 4) * 16;          // byte offset of this lane's k-group
    const int frow = lane & 15;

#pragma unroll
    for (int kk = 0; kk < 2; ++kk) {
        int kbyte = kk * 64 + kgrp;
        bf16x8 afr[4], bfr[4];
#pragma unroll
        for (int f = 0; f < 4; ++f) {
            int ra = wr * 64 + f * 16 + frow;
            afr[f] = *(const bf16x8*)(sA + ra * 128 + (kbyte ^ ((ra & 7) << 4)));
            int rb = wcol * 64 + f * 16 + frow;
            bfr[f] = *(const bf16x8*)(sB + rb * 128 + (kbyte ^ ((rb & 7) << 4)));
        }
#pragma unroll
        for (int fi = 0; fi < 4; ++fi)
#pragma unroll
            for (int fj = 0; fj < 4; ++fj)
                acc[fi][fj] = __builtin_amdgcn_mfma_f32_16x16x32_bf16(
                    afr[fi], bfr[fj], acc[fi][fj], 0, 0, 0);
    }

    // epilogue: sum vm[col] * max(0, dot - 0.2)
    float partial = 0.f;
#pragma unroll
    for (int fj = 0; fj < 4; ++fj) {
        int col = n0 + wcol * 64 + fj * 16 + frow;
        float vmv = (col < NCELL) ? vm[b * NCELL + col] : 0.f;
#pragma unroll
        for (int fi = 0; fi < 4; ++fi)
#pragma unroll
            for (int q = 0; q < 4; ++q)
                partial += vmv * fmaxf(acc[fi][fj][q] - 0.2f, 0.f);
    }
#pragma unroll
    for (int off = 32; off > 0; off >>= 1) partial += __shfl_xor(partial, off);
    if (lane == 0) swave[wv] = partial;
    __syncthreads();
    if (tid == 0) atomicAdd(accum, swave[0] + swave[1] + swave[2] + swave[3]);
}

// ---- kernel 3: sparse s=1 correction: += vm*(250*max(0,1-dot) - max(0,dot-0.2)) ----
__global__ __launch_bounds__(256) void dl_corr_kernel(
    const float* __restrict__ desc, const float* __restrict__ wdesc,
    const float* __restrict__ homog, const float* __restrict__ vm,
    float* __restrict__ accum)
{
    int tid = threadIdx.x;
    int lane = tid & 63;
    int wv = tid >> 6;
    int cell = blockIdx.x * 4 + wv;             // (b, i, j) flat
    int b = cell / NCELL;
    int rem = cell % NCELL;
    int i = rem / WCC, j = rem % WCC;

    const float* H = homog + b * 9;
    float x = (float)(j * 8 + 4), y = (float)(i * 8 + 4);
    float X0 = H[0] * x + H[1] * y + H[2];
    float X1 = H[3] * x + H[4] * y + H[5];
    float X2 = H[6] * x + H[7] * y + H[8];
    float wx = X0 / X2, wy = X1 / X2;

    float dval = desc[(size_t)cell * DD + lane];

    int kc = (int)floorf((wy - 4.f) * 0.125f + 0.5f);
    int lc = (int)floorf((wx - 4.f) * 0.125f + 0.5f);

    float contrib = 0.f;
    for (int dk = -1; dk <= 1; ++dk) {
        for (int dl = -1; dl <= 1; ++dl) {
            int k = kc + dk, l = lc + dl;
            if (k < 0 || k >= HC || l < 0 || l >= WCC) continue;
            float ddy = (float)(k * 8 + 4) - wy;
            float ddx = (float)(l * 8 + 4) - wx;
            if (ddy * ddy + ddx * ddx > 56.25f) continue;   // (g-0.5)^2
            float p = dval * wdesc[((size_t)(b * NCELL + k * WCC + l)) * DD + lane];
#pragma unroll
            for (int off = 32; off > 0; off >>= 1) p += __shfl_xor(p, off);
            float c = 250.f * fmaxf(1.f - p, 0.f) - fmaxf(p - 0.2f, 0.f);
            contrib += vm[b * NCELL + k * WCC + l] * c;
        }
    }

    __shared__ float sp[4];
    if (lane == 0) sp[wv] = contrib;
    __syncthreads();
    if (tid == 0) atomicAdd(accum, sp[0] + sp[1] + sp[2] + sp[3]);
}

// ---- kernel 4: final scalar ----
__global__ void dl_final_kernel(const float* __restrict__ wsf, float* __restrict__ out) {
    out[0] = wsf[0] / (wsf[1] * (float)NCELL);
}

extern "C" void kernel_launch(void* const* d_in, const int* in_sizes, int n_in,
                              void* d_out, int out_size, void* d_ws, size_t ws_size,
                              hipStream_t stream) {
    const float* desc  = (const float*)d_in[0];
    const float* wdesc = (const float*)d_in[1];
    const float* homog = (const float*)d_in[2];
    const float* mask  = (const float*)d_in[3];
    float* out = (float*)d_out;
    float* wsf = (float*)d_ws;
    float* accum = wsf;          // wsf[0] = loss accumulator
    float* vmsum = wsf + 1;      // wsf[1] = sum(vm)
    float* vm = wsf + 16;        // 4*3600 floats

    hipLaunchKernelGGL(dl_init_kernel, dim3(1), dim3(64), 0, stream, wsf);
    hipLaunchKernelGGL(dl_vm_kernel, dim3(3600), dim3(256), 0, stream, mask, vm, vmsum);
    hipLaunchKernelGGL(dl_gemm_loss_kernel, dim3(29, 29, 4), dim3(256), 0, stream,
                       desc, wdesc, vm, accum);
    hipLaunchKernelGGL(dl_corr_kernel, dim3(3600), dim3(256), 0, stream,
                       desc, wdesc, homog, vm, accum);
    hipLaunchKernelGGL(dl_final_kernel, dim3(1), dim3(1), 0, stream, wsf, out);
}

// Round 2
// 59.158 us; speedup vs baseline: 5.0313x; 5.0313x over previous
//
#include <hip/hip_runtime.h>
#include <hip/hip_bf16.h>

#define HC 60
#define WCC 60
#define DD 64
#define NCELL (HC * WCC)      // 3600
#define NBC (4 * NCELL)       // 14400 cells total
#define IMG (HC * 8)          // 480

#define VM_BLOCKS 57          // ceil(14400/256)
#define GEMM_BLOCKS (29 * 29 * 4)
#define CORR_BLOCKS 3600

typedef __bf16 bf16x8 __attribute__((ext_vector_type(8)));
typedef float f32x4 __attribute__((ext_vector_type(4)));

__device__ inline unsigned short f2bf(float f) {
    union { float f; unsigned u; } x; x.f = f;
    unsigned u = x.u;
    unsigned r = (u + 0x7fffu + ((u >> 16) & 1u)) >> 16;  // round-to-nearest-even
    return (unsigned short)r;
}

// ---- kernel 1: vm[cell] = prod over 8x8 block; per-block partial of sum(vm) ----
__global__ __launch_bounds__(256) void dl_vm_kernel(const float* __restrict__ mask,
                                                    float* __restrict__ vm,
                                                    float* __restrict__ vpart) {
    int tid = threadIdx.x;
    int cell = blockIdx.x * 256 + tid;
    float v = 0.f;
    if (cell < NBC) {
        int b = cell / NCELL;
        int rem = cell % NCELL;
        int k = rem / WCC, l = rem % WCC;
        const float* p = mask + (size_t)b * IMG * IMG + (size_t)(k * 8) * IMG + l * 8;
        float prod = 1.f;
#pragma unroll
        for (int dy = 0; dy < 8; ++dy) {
            float4 a0 = *(const float4*)(p + (size_t)dy * IMG);
            float4 a1 = *(const float4*)(p + (size_t)dy * IMG + 4);
            prod *= a0.x * a0.y * a0.z * a0.w * a1.x * a1.y * a1.z * a1.w;
        }
        vm[cell] = prod;
        v = prod;
    }
    // block-reduce sum(v), write one partial per block (no atomics)
#pragma unroll
    for (int off = 32; off > 0; off >>= 1) v += __shfl_xor(v, off);
    __shared__ float sp[4];
    if ((tid & 63) == 0) sp[tid >> 6] = v;
    __syncthreads();
    if (tid == 0) vpart[blockIdx.x] = sp[0] + sp[1] + sp[2] + sp[3];
}

// ---- kernel 2: dense fused GEMM + sum(vm[kl]*max(0, dot-0.2)), per-block partial ----
__global__ __launch_bounds__(256) void dl_gemm_loss_kernel(
    const float* __restrict__ desc, const float* __restrict__ wdesc,
    const float* __restrict__ vm, float* __restrict__ gpart)
{
    __shared__ unsigned char sA[128 * 128];   // 128 rows x 64 bf16 (128B), XOR-swizzled
    __shared__ unsigned char sB[128 * 128];
    __shared__ float swave[4];

    const int b = blockIdx.z;
    const int m0 = blockIdx.x * 128;
    const int n0 = blockIdx.y * 128;
    const int tid = threadIdx.x;
    const int lane = tid & 63;
    const int wv = tid >> 6;

    const float* gA = desc + (size_t)b * NCELL * DD;
    const float* gB = wdesc + (size_t)b * NCELL * DD;

    // stage A and B tiles: f32 global -> bf16 LDS, zero-pad OOB rows (exact: dot=0 -> term 0)
#pragma unroll
    for (int pass = 0; pass < 8; ++pass) {
        int row = pass * 16 + (tid >> 4);       // 0..127
        int c4 = (tid & 15) * 4;                // f32 column
        int cb = (c4 * 2) ^ ((row & 7) << 4);   // swizzled byte offset
        {
            int gr = m0 + row;
            float4 v = make_float4(0.f, 0.f, 0.f, 0.f);
            if (gr < NCELL) v = *(const float4*)(gA + (size_t)gr * DD + c4);
            ushort4 p;
            p.x = f2bf(v.x); p.y = f2bf(v.y); p.z = f2bf(v.z); p.w = f2bf(v.w);
            *(ushort4*)(sA + row * 128 + cb) = p;
        }
        {
            int gr = n0 + row;
            float4 v = make_float4(0.f, 0.f, 0.f, 0.f);
            if (gr < NCELL) v = *(const float4*)(gB + (size_t)gr * DD + c4);
            ushort4 p;
            p.x = f2bf(v.x); p.y = f2bf(v.y); p.z = f2bf(v.z); p.w = f2bf(v.w);
            *(ushort4*)(sB + row * 128 + cb) = p;
        }
    }
    __syncthreads();

    const int wr = wv >> 1, wcol = wv & 1;      // wave -> 64x64 subtile
    f32x4 acc[4][4];
#pragma unroll
    for (int i2 = 0; i2 < 4; ++i2)
#pragma unroll
        for (int j2 = 0; j2 < 4; ++j2)
            acc[i2][j2] = (f32x4)(0.f);

    const int kgrp = (lane >> 4) * 16;          // byte offset of this lane's k-group
    const int frow = lane & 15;

#pragma unroll
    for (int kk = 0; kk < 2; ++kk) {
        int kbyte = kk * 64 + kgrp;
        bf16x8 afr[4], bfr[4];
#pragma unroll
        for (int f = 0; f < 4; ++f) {
            int ra = wr * 64 + f * 16 + frow;
            afr[f] = *(const bf16x8*)(sA + ra * 128 + (kbyte ^ ((ra & 7) << 4)));
            int rb = wcol * 64 + f * 16 + frow;
            bfr[f] = *(const bf16x8*)(sB + rb * 128 + (kbyte ^ ((rb & 7) << 4)));
        }
#pragma unroll
        for (int fi = 0; fi < 4; ++fi)
#pragma unroll
            for (int fj = 0; fj < 4; ++fj)
                acc[fi][fj] = __builtin_amdgcn_mfma_f32_16x16x32_bf16(
                    afr[fi], bfr[fj], acc[fi][fj], 0, 0, 0);
    }

    // epilogue: sum vm[col] * max(0, dot - 0.2)
    float partial = 0.f;
#pragma unroll
    for (int fj = 0; fj < 4; ++fj) {
        int col = n0 + wcol * 64 + fj * 16 + frow;
        float vmv = (col < NCELL) ? vm[b * NCELL + col] : 0.f;
#pragma unroll
        for (int fi = 0; fi < 4; ++fi)
#pragma unroll
            for (int q = 0; q < 4; ++q)
                partial += vmv * fmaxf(acc[fi][fj][q] - 0.2f, 0.f);
    }
#pragma unroll
    for (int off = 32; off > 0; off >>= 1) partial += __shfl_xor(partial, off);
    if (lane == 0) swave[wv] = partial;
    __syncthreads();
    if (tid == 0) {
        int slot = blockIdx.x + 29 * (blockIdx.y + 29 * blockIdx.z);
        gpart[slot] = swave[0] + swave[1] + swave[2] + swave[3];
    }
}

// ---- kernel 3: sparse s=1 correction: += vm*(250*max(0,1-dot) - max(0,dot-0.2)) ----
__global__ __launch_bounds__(256) void dl_corr_kernel(
    const float* __restrict__ desc, const float* __restrict__ wdesc,
    const float* __restrict__ homog, const float* __restrict__ vm,
    float* __restrict__ cpart)
{
    int tid = threadIdx.x;
    int lane = tid & 63;
    int wv = tid >> 6;
    int cell = blockIdx.x * 4 + wv;             // (b, i, j) flat
    int b = cell / NCELL;
    int rem = cell % NCELL;
    int i = rem / WCC, j = rem % WCC;

    const float* H = homog + b * 9;
    float x = (float)(j * 8 + 4), y = (float)(i * 8 + 4);
    float X0 = H[0] * x + H[1] * y + H[2];
    float X1 = H[3] * x + H[4] * y + H[5];
    float X2 = H[6] * x + H[7] * y + H[8];
    float wx = X0 / X2, wy = X1 / X2;

    float dval = desc[(size_t)cell * DD + lane];

    int kc = (int)floorf((wy - 4.f) * 0.125f + 0.5f);
    int lc = (int)floorf((wx - 4.f) * 0.125f + 0.5f);

    float contrib = 0.f;
    for (int dk = -1; dk <= 1; ++dk) {
        for (int dl = -1; dl <= 1; ++dl) {
            int k = kc + dk, l = lc + dl;
            if (k < 0 || k >= HC || l < 0 || l >= WCC) continue;
            float ddy = (float)(k * 8 + 4) - wy;
            float ddx = (float)(l * 8 + 4) - wx;
            if (ddy * ddy + ddx * ddx > 56.25f) continue;   // (g-0.5)^2
            float p = dval * wdesc[((size_t)(b * NCELL + k * WCC + l)) * DD + lane];
#pragma unroll
            for (int off = 32; off > 0; off >>= 1) p += __shfl_xor(p, off);
            float c = 250.f * fmaxf(1.f - p, 0.f) - fmaxf(p - 0.2f, 0.f);
            contrib += vm[b * NCELL + k * WCC + l] * c;
        }
    }

    __shared__ float sp[4];
    if (lane == 0) sp[wv] = contrib;
    __syncthreads();
    if (tid == 0) cpart[blockIdx.x] = sp[0] + sp[1] + sp[2] + sp[3];
}

// ---- kernel 4: final reduction of all per-block partials -> scalar ----
__global__ __launch_bounds__(256) void dl_final_kernel(
    const float* __restrict__ vpart, const float* __restrict__ gpart,
    const float* __restrict__ cpart, float* __restrict__ out)
{
    int tid = threadIdx.x;
    float ls = 0.f, vs = 0.f;
    for (int i = tid; i < GEMM_BLOCKS; i += 256) ls += gpart[i];
    for (int i = tid; i < CORR_BLOCKS; i += 256) ls += cpart[i];
    for (int i = tid; i < VM_BLOCKS; i += 256) vs += vpart[i];
#pragma unroll
    for (int off = 32; off > 0; off >>= 1) {
        ls += __shfl_xor(ls, off);
        vs += __shfl_xor(vs, off);
    }
    __shared__ float sl[4], sv[4];
    if ((tid & 63) == 0) { sl[tid >> 6] = ls; sv[tid >> 6] = vs; }
    __syncthreads();
    if (tid == 0) {
        float L = sl[0] + sl[1] + sl[2] + sl[3];
        float V = sv[0] + sv[1] + sv[2] + sv[3];
        out[0] = L / (V * (float)NCELL);
    }
}

extern "C" void kernel_launch(void* const* d_in, const int* in_sizes, int n_in,
                              void* d_out, int out_size, void* d_ws, size_t ws_size,
                              hipStream_t stream) {
    const float* desc  = (const float*)d_in[0];
    const float* wdesc = (const float*)d_in[1];
    const float* homog = (const float*)d_in[2];
    const float* mask  = (const float*)d_in[3];
    float* out = (float*)d_out;
    float* wsf = (float*)d_ws;

    // workspace layout (floats); every slot fully overwritten each call -> no init needed
    float* vpart = wsf;                        // [VM_BLOCKS]
    float* vm    = wsf + 64;                   // [NBC]
    float* gpart = wsf + 64 + NBC;             // [GEMM_BLOCKS]
    float* cpart = wsf + 64 + NBC + GEMM_BLOCKS; // [CORR_BLOCKS]

    hipLaunchKernelGGL(dl_vm_kernel, dim3(VM_BLOCKS), dim3(256), 0, stream, mask, vm, vpart);
    hipLaunchKernelGGL(dl_gemm_loss_kernel, dim3(29, 29, 4), dim3(256), 0, stream,
                       desc, wdesc, vm, gpart);
    hipLaunchKernelGGL(dl_corr_kernel, dim3(CORR_BLOCKS), dim3(256), 0, stream,
                       desc, wdesc, homog, vm, cpart);
    hipLaunchKernelGGL(dl_final_kernel, dim3(1), dim3(256), 0, stream,
                       vpart, gpart, cpart, out);
}

// Round 3
// 43.087 us; speedup vs baseline: 6.9081x; 1.3730x over previous
//
#include <hip/hip_runtime.h>
#include <hip/hip_bf16.h>

#define HC 60
#define WCC 60
#define DD 64
#define NCELL (HC * WCC)      // 3600
#define NBC (4 * NCELL)       // 14400 cells total
#define IMG (HC * 8)          // 480
#define MPAD 3840             // 15 * 256, zero-padded rows
#define NT 15                 // 256-tiles per dim

#define VM_BLOCKS 57          // ceil(14400/256)
#define CVT_BLOCKS 480        // 4*3840*64/8 / 256
#define GEMM_BLOCKS (NT * NT * 4)   // 900
#define CORR_BLOCKS 1800      // 14400 cells / 8 waves

typedef __bf16 bf16x8 __attribute__((ext_vector_type(8)));
typedef float f32x4 __attribute__((ext_vector_type(4)));
typedef unsigned short u16x8 __attribute__((ext_vector_type(8)));

__device__ inline unsigned short f2bf(float f) {
    union { float f; unsigned u; } x; x.f = f;
    unsigned u = x.u;
    unsigned r = (u + 0x7fffu + ((u >> 16) & 1u)) >> 16;  // round-to-nearest-even
    return (unsigned short)r;
}

__device__ inline void gload_lds16(const void* g, void* l) {
    __builtin_amdgcn_global_load_lds(
        (const __attribute__((address_space(1))) unsigned int*)g,
        (__attribute__((address_space(3))) unsigned int*)l, 16, 0, 0);
}

// ---- kernel 0: f32 -> bf16 pre-convert, padded to MPAD rows/batch (pad rows = 0) ----
__global__ __launch_bounds__(256) void dl_cvt_kernel(const float* __restrict__ desc,
                                                     const float* __restrict__ wdesc,
                                                     unsigned short* __restrict__ descb,
                                                     unsigned short* __restrict__ wdescb) {
    int t = blockIdx.x * 256 + threadIdx.x;   // 0 .. 122879
    int brow = t >> 3;                        // b*MPAD + row
    int col = (t & 7) * 8;
    int b = brow / MPAD;
    int row = brow - b * MPAD;
    u16x8 oa = (u16x8)0, ob = (u16x8)0;
    if (row < NCELL) {
        size_t src = ((size_t)(b * NCELL + row)) * DD + col;
        float4 a0 = *(const float4*)(desc + src);
        float4 a1 = *(const float4*)(desc + src + 4);
        float4 b0 = *(const float4*)(wdesc + src);
        float4 b1 = *(const float4*)(wdesc + src + 4);
        oa[0] = f2bf(a0.x); oa[1] = f2bf(a0.y); oa[2] = f2bf(a0.z); oa[3] = f2bf(a0.w);
        oa[4] = f2bf(a1.x); oa[5] = f2bf(a1.y); oa[6] = f2bf(a1.z); oa[7] = f2bf(a1.w);
        ob[0] = f2bf(b0.x); ob[1] = f2bf(b0.y); ob[2] = f2bf(b0.z); ob[3] = f2bf(b0.w);
        ob[4] = f2bf(b1.x); ob[5] = f2bf(b1.y); ob[6] = f2bf(b1.z); ob[7] = f2bf(b1.w);
    }
    size_t dst = (size_t)brow * DD + col;
    *(u16x8*)(descb + dst) = oa;
    *(u16x8*)(wdescb + dst) = ob;
}

// ---- kernel 1: vm[cell] = prod over 8x8 block; per-block partial of sum(vm) ----
__global__ __launch_bounds__(256) void dl_vm_kernel(const float* __restrict__ mask,
                                                    float* __restrict__ vm,
                                                    float* __restrict__ vpart) {
    int tid = threadIdx.x;
    int cell = blockIdx.x * 256 + tid;
    float v = 0.f;
    if (cell < NBC) {
        int b = cell / NCELL;
        int rem = cell % NCELL;
        int k = rem / WCC, l = rem % WCC;
        const float* p = mask + (size_t)b * IMG * IMG + (size_t)(k * 8) * IMG + l * 8;
        float prod = 1.f;
#pragma unroll
        for (int dy = 0; dy < 8; ++dy) {
            float4 a0 = *(const float4*)(p + (size_t)dy * IMG);
            float4 a1 = *(const float4*)(p + (size_t)dy * IMG + 4);
            prod *= a0.x * a0.y * a0.z * a0.w * a1.x * a1.y * a1.z * a1.w;
        }
        vm[cell] = prod;
        v = prod;
    }
#pragma unroll
    for (int off = 32; off > 0; off >>= 1) v += __shfl_xor(v, off);
    __shared__ float sp[4];
    if ((tid & 63) == 0) sp[tid >> 6] = v;
    __syncthreads();
    if (tid == 0) vpart[blockIdx.x] = sp[0] + sp[1] + sp[2] + sp[3];
}

// ---- kernel 2: 256x256-tile GEMM + sum(vm[col]*max(0, dot-0.2)), per-block partial ----
__global__ __launch_bounds__(512, 2) void dl_gemm_loss_kernel(
    const unsigned short* __restrict__ descb, const unsigned short* __restrict__ wdescb,
    const float* __restrict__ vm, float* __restrict__ gpart)
{
    __shared__ unsigned char sA[256 * 128];   // 256 rows x 64 bf16, XOR-swizzled
    __shared__ unsigned char sB[256 * 128];
    __shared__ float swave[8];

    const int b = blockIdx.z;
    const int m0 = blockIdx.x * 256;
    const int n0 = blockIdx.y * 256;
    const int tid = threadIdx.x;
    const int lane = tid & 63;
    const int wv = tid >> 6;

    const unsigned char* gA = (const unsigned char*)(descb + (size_t)b * MPAD * DD) + (size_t)m0 * 128;
    const unsigned char* gB = (const unsigned char*)(wdescb + (size_t)b * MPAD * DD) + (size_t)n0 * 128;

    // stage: wave wv loads rows [wv*32, wv*32+32). LDS dest linear (base+lane*16);
    // swizzle achieved by pre-swizzling the per-lane GLOBAL source (m173 pattern).
    {
        const int swz = ((lane & 7) ^ (lane >> 3)) << 4;
        const int lrow = lane >> 3;                     // 0..7
#pragma unroll
        for (int t = 0; t < 4; ++t) {
            int row = wv * 32 + t * 8 + lrow;
            gload_lds16(gA + (size_t)row * 128 + swz, sA + wv * 4096 + t * 1024);
            gload_lds16(gB + (size_t)row * 128 + swz, sB + wv * 4096 + t * 1024);
        }
    }
    __syncthreads();

    const int wr = wv >> 2;          // 0..1 : 128-row block
    const int wc = wv & 3;           // 0..3 : 64-col block
    const int frow = lane & 15;
    const int kg = (lane >> 4) * 16; // byte offset of this lane's k-group

    f32x4 acc[8][4];
#pragma unroll
    for (int i2 = 0; i2 < 8; ++i2)
#pragma unroll
        for (int j2 = 0; j2 < 4; ++j2)
            acc[i2][j2] = (f32x4)(0.f);

#pragma unroll
    for (int kk = 0; kk < 2; ++kk) {
        int kbyte = kk * 64 + kg;
        bf16x8 afr[8], bfr[4];
#pragma unroll
        for (int f = 0; f < 8; ++f) {
            int ra = wr * 128 + f * 16 + frow;
            afr[f] = *(const bf16x8*)(sA + ra * 128 + (kbyte ^ ((ra & 7) << 4)));
        }
#pragma unroll
        for (int f = 0; f < 4; ++f) {
            int rb = wc * 64 + f * 16 + frow;
            bfr[f] = *(const bf16x8*)(sB + rb * 128 + (kbyte ^ ((rb & 7) << 4)));
        }
#pragma unroll
        for (int fi = 0; fi < 8; ++fi)
#pragma unroll
            for (int fj = 0; fj < 4; ++fj)
                acc[fi][fj] = __builtin_amdgcn_mfma_f32_16x16x32_bf16(
                    afr[fi], bfr[fj], acc[fi][fj], 0, 0, 0);
    }

    // epilogue: sum vm[col] * max(0, dot - 0.2); pad rows give dot=0 -> term 0
    float partial = 0.f;
#pragma unroll
    for (int fj = 0; fj < 4; ++fj) {
        int col = n0 + wc * 64 + fj * 16 + frow;
        float vmv = (col < NCELL) ? vm[b * NCELL + col] : 0.f;
#pragma unroll
        for (int fi = 0; fi < 8; ++fi)
#pragma unroll
            for (int q = 0; q < 4; ++q)
                partial += vmv * fmaxf(acc[fi][fj][q] - 0.2f, 0.f);
    }
#pragma unroll
    for (int off = 32; off > 0; off >>= 1) partial += __shfl_xor(partial, off);
    if (lane == 0) swave[wv] = partial;
    __syncthreads();
    if (tid == 0) {
        float s = 0.f;
#pragma unroll
        for (int w = 0; w < 8; ++w) s += swave[w];
        gpart[blockIdx.x + NT * (blockIdx.y + NT * b)] = s;
    }
}

// ---- kernel 3: sparse s=1 correction: += vm*(250*max(0,1-dot) - max(0,dot-0.2)) ----
__global__ __launch_bounds__(512) void dl_corr_kernel(
    const float* __restrict__ desc, const float* __restrict__ wdesc,
    const float* __restrict__ homog, const float* __restrict__ vm,
    float* __restrict__ cpart)
{
    int tid = threadIdx.x;
    int lane = tid & 63;
    int wv = tid >> 6;
    int cell = blockIdx.x * 8 + wv;             // (b, i, j) flat
    int b = cell / NCELL;
    int rem = cell % NCELL;
    int i = rem / WCC, j = rem % WCC;

    const float* H = homog + b * 9;
    float x = (float)(j * 8 + 4), y = (float)(i * 8 + 4);
    float X0 = H[0] * x + H[1] * y + H[2];
    float X1 = H[3] * x + H[4] * y + H[5];
    float X2 = H[6] * x + H[7] * y + H[8];
    float wx = X0 / X2, wy = X1 / X2;

    float dval = desc[(size_t)cell * DD + lane];

    int kc = (int)floorf((wy - 4.f) * 0.125f + 0.5f);
    int lc = (int)floorf((wx - 4.f) * 0.125f + 0.5f);

    float contrib = 0.f;
    for (int dk = -1; dk <= 1; ++dk) {
        for (int dl = -1; dl <= 1; ++dl) {
            int k = kc + dk, l = lc + dl;
            if (k < 0 || k >= HC || l < 0 || l >= WCC) continue;
            float ddy = (float)(k * 8 + 4) - wy;
            float ddx = (float)(l * 8 + 4) - wx;
            if (ddy * ddy + ddx * ddx > 56.25f) continue;   // (g-0.5)^2
            float p = dval * wdesc[((size_t)(b * NCELL + k * WCC + l)) * DD + lane];
#pragma unroll
            for (int off = 32; off > 0; off >>= 1) p += __shfl_xor(p, off);
            float c = 250.f * fmaxf(1.f - p, 0.f) - fmaxf(p - 0.2f, 0.f);
            contrib += vm[b * NCELL + k * WCC + l] * c;
        }
    }

    __shared__ float sp[8];
    if (lane == 0) sp[wv] = contrib;
    __syncthreads();
    if (tid == 0) {
        float s = 0.f;
#pragma unroll
        for (int w = 0; w < 8; ++w) s += sp[w];
        cpart[blockIdx.x] = s;
    }
}

// ---- kernel 4: final reduction of all per-block partials -> scalar ----
__global__ __launch_bounds__(256) void dl_final_kernel(
    const float* __restrict__ vpart, const float* __restrict__ gpart,
    const float* __restrict__ cpart, float* __restrict__ out)
{
    int tid = threadIdx.x;
    float ls = 0.f, vs = 0.f;
    for (int i = tid; i < GEMM_BLOCKS; i += 256) ls += gpart[i];
    for (int i = tid; i < CORR_BLOCKS; i += 256) ls += cpart[i];
    for (int i = tid; i < VM_BLOCKS; i += 256) vs += vpart[i];
#pragma unroll
    for (int off = 32; off > 0; off >>= 1) {
        ls += __shfl_xor(ls, off);
        vs += __shfl_xor(vs, off);
    }
    __shared__ float sl[4], sv[4];
    if ((tid & 63) == 0) { sl[tid >> 6] = ls; sv[tid >> 6] = vs; }
    __syncthreads();
    if (tid == 0) {
        float L = sl[0] + sl[1] + sl[2] + sl[3];
        float V = sv[0] + sv[1] + sv[2] + sv[3];
        out[0] = L / (V * (float)NCELL);
    }
}

extern "C" void kernel_launch(void* const* d_in, const int* in_sizes, int n_in,
                              void* d_out, int out_size, void* d_ws, size_t ws_size,
                              hipStream_t stream) {
    const float* desc  = (const float*)d_in[0];
    const float* wdesc = (const float*)d_in[1];
    const float* homog = (const float*)d_in[2];
    const float* mask  = (const float*)d_in[3];
    float* out = (float*)d_out;
    float* wsf = (float*)d_ws;

    // workspace layout (floats); every slot fully overwritten each call -> no init needed
    float* vpart = wsf;                          // [57]
    float* vm    = wsf + 64;                     // [14400]
    float* gpart = wsf + 64 + NBC;               // [900]
    float* cpart = wsf + 64 + NBC + GEMM_BLOCKS; // [1800]
    unsigned short* descb  = (unsigned short*)(wsf + 17408);     // [4*3840*64] bf16, 256B-aligned
    unsigned short* wdescb = descb + (size_t)4 * MPAD * DD;

    hipLaunchKernelGGL(dl_cvt_kernel, dim3(CVT_BLOCKS), dim3(256), 0, stream,
                       desc, wdesc, descb, wdescb);
    hipLaunchKernelGGL(dl_vm_kernel, dim3(VM_BLOCKS), dim3(256), 0, stream, mask, vm, vpart);
    hipLaunchKernelGGL(dl_gemm_loss_kernel, dim3(NT, NT, 4), dim3(512), 0, stream,
                       descb, wdescb, vm, gpart);
    hipLaunchKernelGGL(dl_corr_kernel, dim3(CORR_BLOCKS), dim3(512), 0, stream,
                       desc, wdesc, homog, vm, cpart);
    hipLaunchKernelGGL(dl_final_kernel, dim3(1), dim3(256), 0, stream,
                       vpart, gpart, cpart, out);
}

// Round 4
// 39.163 us; speedup vs baseline: 7.6001x; 1.1002x over previous
//
#include <hip/hip_runtime.h>
#include <hip/hip_bf16.h>

#define HC 60
#define WCC 60
#define DD 64
#define NCELL (HC * WCC)      // 3600
#define NBC (4 * NCELL)       // 14400
#define IMG (HC * 8)          // 480
#define MPAD 3840             // 15 * 256 zero-padded rows per batch
#define NT 15

#define CVT_BLOCKS 480        // 4*3840*64/8 / 256
#define VM_BLOCKS 57          // ceil(14400/256)
#define WC_BLOCKS 60          // 4*3840/256
#define PREP_BLOCKS (CVT_BLOCKS + VM_BLOCKS + WC_BLOCKS)   // 597
#define GEMM_BLOCKS (NT * NT * 4)   // 900

typedef __bf16 bf16x8 __attribute__((ext_vector_type(8)));
typedef float f32x4 __attribute__((ext_vector_type(4)));
typedef unsigned short u16x8 __attribute__((ext_vector_type(8)));

__device__ inline unsigned short f2bf(float f) {
    union { float f; unsigned u; } x; x.f = f;
    unsigned u = x.u;
    unsigned r = (u + 0x7fffu + ((u >> 16) & 1u)) >> 16;  // RNE
    return (unsigned short)r;
}

__device__ inline void gload_lds16(const void* g, void* l) {
    __builtin_amdgcn_global_load_lds(
        (const __attribute__((address_space(1))) unsigned int*)g,
        (__attribute__((address_space(3))) unsigned int*)l, 16, 0, 0);
}

__device__ inline int div60(int v) { return (v * 17477) >> 20; }  // exact for 0<=v<3840

// ---- kernel 1 (fused prep): f32->bf16 convert (padded), vm + partial sum, warped centers ----
__global__ __launch_bounds__(256) void dl_prep_kernel(
    const float* __restrict__ desc, const float* __restrict__ wdesc,
    const float* __restrict__ homog, const float* __restrict__ mask,
    unsigned short* __restrict__ descb, unsigned short* __restrict__ wdescb,
    float* __restrict__ vm, float* __restrict__ vpart, float2* __restrict__ wcent)
{
    const int bid = blockIdx.x;
    const int tid = threadIdx.x;

    if (bid < CVT_BLOCKS) {
        int t = bid * 256 + tid;
        int brow = t >> 3;
        int col = (t & 7) * 8;
        int b = brow / MPAD;
        int row = brow - b * MPAD;
        u16x8 oa = (u16x8)0, ob = (u16x8)0;
        if (row < NCELL) {
            size_t src = ((size_t)(b * NCELL + row)) * DD + col;
            float4 a0 = *(const float4*)(desc + src);
            float4 a1 = *(const float4*)(desc + src + 4);
            float4 b0 = *(const float4*)(wdesc + src);
            float4 b1 = *(const float4*)(wdesc + src + 4);
            oa[0] = f2bf(a0.x); oa[1] = f2bf(a0.y); oa[2] = f2bf(a0.z); oa[3] = f2bf(a0.w);
            oa[4] = f2bf(a1.x); oa[5] = f2bf(a1.y); oa[6] = f2bf(a1.z); oa[7] = f2bf(a1.w);
            ob[0] = f2bf(b0.x); ob[1] = f2bf(b0.y); ob[2] = f2bf(b0.z); ob[3] = f2bf(b0.w);
            ob[4] = f2bf(b1.x); ob[5] = f2bf(b1.y); ob[6] = f2bf(b1.z); ob[7] = f2bf(b1.w);
        }
        size_t dst = (size_t)brow * DD + col;
        *(u16x8*)(descb + dst) = oa;
        *(u16x8*)(wdescb + dst) = ob;
    } else if (bid < CVT_BLOCKS + VM_BLOCKS) {
        int vb = bid - CVT_BLOCKS;
        int cell = vb * 256 + tid;
        float v = 0.f;
        if (cell < NBC) {
            int b = cell / NCELL;
            int rem = cell % NCELL;
            int k = rem / WCC, l = rem % WCC;
            const float* p = mask + (size_t)b * IMG * IMG + (size_t)(k * 8) * IMG + l * 8;
            float prod = 1.f;
#pragma unroll
            for (int dy = 0; dy < 8; ++dy) {
                float4 a0 = *(const float4*)(p + (size_t)dy * IMG);
                float4 a1 = *(const float4*)(p + (size_t)dy * IMG + 4);
                prod *= a0.x * a0.y * a0.z * a0.w * a1.x * a1.y * a1.z * a1.w;
            }
            vm[cell] = prod;
            v = prod;
        }
#pragma unroll
        for (int off = 32; off > 0; off >>= 1) v += __shfl_xor(v, off);
        __shared__ float sp[4];
        if ((tid & 63) == 0) sp[tid >> 6] = v;
        __syncthreads();
        if (tid == 0) vpart[vb] = sp[0] + sp[1] + sp[2] + sp[3];
    } else {
        int t = (bid - CVT_BLOCKS - VM_BLOCKS) * 256 + tid;   // 0 .. 15359
        int b = t / MPAD;
        int r = t - b * MPAD;
        float2 o;
        if (r < NCELL) {
            int i = div60(r);
            int j = r - i * WCC;
            const float* H = homog + b * 9;
            float x = (float)(j * 8 + 4), y = (float)(i * 8 + 4);
            float X2 = H[6] * x + H[7] * y + H[8];
            o.x = (H[3] * x + H[4] * y + H[5]) / X2;   // wy
            o.y = (H[0] * x + H[1] * y + H[2]) / X2;   // wx
        } else {
            o.x = 1e9f; o.y = 1e9f;                    // pad rows: s = 0
        }
        wcent[t] = o;
    }
}

// ---- kernel 2: 256x256-tile GEMM with fully fused loss epilogue ----
__global__ __launch_bounds__(512, 2) void dl_gemm_loss_kernel(
    const unsigned short* __restrict__ descb, const unsigned short* __restrict__ wdescb,
    const float* __restrict__ vm, const float2* __restrict__ wcent,
    float* __restrict__ gpart)
{
    __shared__ unsigned char sA[256 * 128];   // 256 rows x 64 bf16, XOR-swizzled
    __shared__ unsigned char sB[256 * 128];
    __shared__ float2 swcent[256];
    __shared__ float swave[8];

    const int b = blockIdx.z;
    const int m0 = blockIdx.x * 256;
    const int n0 = blockIdx.y * 256;
    const int tid = threadIdx.x;
    const int lane = tid & 63;
    const int wv = tid >> 6;

    const unsigned char* gA = (const unsigned char*)(descb + (size_t)b * MPAD * DD) + (size_t)m0 * 128;
    const unsigned char* gB = (const unsigned char*)(wdescb + (size_t)b * MPAD * DD) + (size_t)n0 * 128;

    // stage tiles: LDS dest linear, swizzle via pre-swizzled global source (m173)
    {
        const int swz = ((lane & 7) ^ (lane >> 3)) << 4;
        const int lrow = lane >> 3;
#pragma unroll
        for (int t = 0; t < 4; ++t) {
            int row = wv * 32 + t * 8 + lrow;
            gload_lds16(gA + (size_t)row * 128 + swz, sA + wv * 4096 + t * 1024);
            gload_lds16(gB + (size_t)row * 128 + swz, sB + wv * 4096 + t * 1024);
        }
    }
    // stage warped centers for this block's 256 rows
    if (tid < 256) swcent[tid] = wcent[b * MPAD + m0 + tid];
    __syncthreads();

    const int wr = wv >> 2;          // 0..1 : 128-row half
    const int wc = wv & 3;           // 0..3 : 64-col slice
    const int frow = lane & 15;
    const int kg = (lane >> 4) * 16;

    f32x4 acc[8][4];
#pragma unroll
    for (int i2 = 0; i2 < 8; ++i2)
#pragma unroll
        for (int j2 = 0; j2 < 4; ++j2)
            acc[i2][j2] = (f32x4)(0.f);

#pragma unroll
    for (int kk = 0; kk < 2; ++kk) {
        int kbyte = kk * 64 + kg;
        bf16x8 afr[8], bfr[4];
#pragma unroll
        for (int f = 0; f < 8; ++f) {
            int ra = wr * 128 + f * 16 + frow;
            afr[f] = *(const bf16x8*)(sA + ra * 128 + (kbyte ^ ((ra & 7) << 4)));
        }
#pragma unroll
        for (int f = 0; f < 4; ++f) {
            int rb = wc * 64 + f * 16 + frow;
            bfr[f] = *(const bf16x8*)(sB + rb * 128 + (kbyte ^ ((rb & 7) << 4)));
        }
#pragma unroll
        for (int fi = 0; fi < 8; ++fi)
#pragma unroll
            for (int fj = 0; fj < 4; ++fj)
                acc[fi][fj] = __builtin_amdgcn_mfma_f32_16x16x32_bf16(
                    afr[fi], bfr[fj], acc[fi][fj], 0, 0, 0);
    }

    // --- fused loss epilogue ---
    // col geometry (4 cols per lane)
    float cyv[4], cxv[4], vmv[4];
#pragma unroll
    for (int fj = 0; fj < 4; ++fj) {
        int col = n0 + wc * 64 + fj * 16 + frow;
        int k = div60(col);
        int l = col - k * WCC;
        cyv[fj] = (float)(k * 8 + 4);
        cxv[fj] = (float)(l * 8 + 4);
        vmv[fj] = (col < NCELL) ? vm[b * NCELL + col] : 0.f;
    }

    // wave-uniform test: can any of this wave's 128 rows hit s=1 in its 64 cols?
    float wlo = 1e30f, whi = -1e30f;
#pragma unroll
    for (int t = 0; t < 2; ++t) {
        float wyv = swcent[wr * 128 + t * 64 + lane].x;
        wlo = fminf(wlo, wyv); whi = fmaxf(whi, wyv);
    }
#pragma unroll
    for (int off = 32; off > 0; off >>= 1) {
        wlo = fminf(wlo, __shfl_xor(wlo, off));
        whi = fmaxf(whi, __shfl_xor(whi, off));
    }
    int c0 = n0 + wc * 64, c1 = c0 + 63;
    float cy0 = (float)(div60(c0) * 8 + 4) - 7.5f;
    float cy1 = (float)(div60(c1) * 8 + 4) + 7.5f;
    bool full = (whi >= cy0) && (wlo <= cy1);

    float partial = 0.f;
    if (full) {
#pragma unroll
        for (int fi = 0; fi < 8; ++fi) {
#pragma unroll
            for (int q = 0; q < 4; ++q) {
                float2 w2 = swcent[wr * 128 + fi * 16 + (lane >> 4) * 4 + q];
#pragma unroll
                for (int fj = 0; fj < 4; ++fj) {
                    float dot = acc[fi][fj][q];
                    float ddy = cyv[fj] - w2.x;
                    float ddx = cxv[fj] - w2.y;
                    float d2 = ddy * ddy + ddx * ddx;
                    float rn = fmaxf(dot - 0.2f, 0.f);
                    float rp = 250.f * fmaxf(1.f - dot, 0.f);
                    float sel = (d2 <= 56.25f) ? rp : rn;
                    partial += vmv[fj] * sel;
                }
            }
        }
    } else {
#pragma unroll
        for (int fi = 0; fi < 8; ++fi)
#pragma unroll
            for (int fj = 0; fj < 4; ++fj)
#pragma unroll
                for (int q = 0; q < 4; ++q)
                    partial += vmv[fj] * fmaxf(acc[fi][fj][q] - 0.2f, 0.f);
    }

#pragma unroll
    for (int off = 32; off > 0; off >>= 1) partial += __shfl_xor(partial, off);
    if (lane == 0) swave[wv] = partial;
    __syncthreads();
    if (tid == 0) {
        float s = 0.f;
#pragma unroll
        for (int w = 0; w < 8; ++w) s += swave[w];
        gpart[blockIdx.x + NT * (blockIdx.y + NT * b)] = s;
    }
}

// ---- kernel 3: final reduction -> scalar ----
__global__ __launch_bounds__(256) void dl_final_kernel(
    const float* __restrict__ vpart, const float* __restrict__ gpart,
    float* __restrict__ out)
{
    int tid = threadIdx.x;
    float ls = 0.f, vs = 0.f;
    for (int i = tid; i < GEMM_BLOCKS; i += 256) ls += gpart[i];
    for (int i = tid; i < VM_BLOCKS; i += 256) vs += vpart[i];
#pragma unroll
    for (int off = 32; off > 0; off >>= 1) {
        ls += __shfl_xor(ls, off);
        vs += __shfl_xor(vs, off);
    }
    __shared__ float sl[4], sv[4];
    if ((tid & 63) == 0) { sl[tid >> 6] = ls; sv[tid >> 6] = vs; }
    __syncthreads();
    if (tid == 0) {
        float L = sl[0] + sl[1] + sl[2] + sl[3];
        float V = sv[0] + sv[1] + sv[2] + sv[3];
        out[0] = L / (V * (float)NCELL);
    }
}

extern "C" void kernel_launch(void* const* d_in, const int* in_sizes, int n_in,
                              void* d_out, int out_size, void* d_ws, size_t ws_size,
                              hipStream_t stream) {
    const float* desc  = (const float*)d_in[0];
    const float* wdesc = (const float*)d_in[1];
    const float* homog = (const float*)d_in[2];
    const float* mask  = (const float*)d_in[3];
    float* out = (float*)d_out;
    float* wsf = (float*)d_ws;

    // workspace layout (floats); every slot fully overwritten each call
    float* vpart = wsf;                           // [57]
    float* vm    = wsf + 64;                      // [14400]
    float* gpart = wsf + 64 + NBC;                // [900]
    float2* wcent = (float2*)(wsf + 15400);       // [4*3840] float2 (8B aligned)
    unsigned short* descb  = (unsigned short*)(wsf + 46208);   // 256B-aligned
    unsigned short* wdescb = descb + (size_t)4 * MPAD * DD;

    hipLaunchKernelGGL(dl_prep_kernel, dim3(PREP_BLOCKS), dim3(256), 0, stream,
                       desc, wdesc, homog, mask, descb, wdescb, vm, vpart, wcent);
    hipLaunchKernelGGL(dl_gemm_loss_kernel, dim3(NT, NT, 4), dim3(512), 0, stream,
                       descb, wdescb, vm, wcent, gpart);
    hipLaunchKernelGGL(dl_final_kernel, dim3(1), dim3(256), 0, stream,
                       vpart, gpart, out);
}

// Round 5
// 36.705 us; speedup vs baseline: 8.1091x; 1.0670x over previous
//
#include <hip/hip_runtime.h>
#include <hip/hip_bf16.h>

#define HC 60
#define WCC 60
#define DD 64
#define NCELL (HC * WCC)      // 3600
#define NBC (4 * NCELL)       // 14400
#define IMG (HC * 8)          // 480
#define MPAD 3840             // 30 * 128 zero-padded rows per batch
#define NT2 30                // 128-tiles per dim

#define CVT_BLOCKS 480        // 4*3840*64/8 / 256
#define VM_BLOCKS 57          // ceil(14400/256)
#define WC_BLOCKS 60          // 4*3840/256
#define PREP_BLOCKS (CVT_BLOCKS + VM_BLOCKS + WC_BLOCKS)   // 597
#define GEMM_BLOCKS (NT2 * NT2 * 4)   // 3600

typedef __bf16 bf16x8 __attribute__((ext_vector_type(8)));
typedef float f32x4 __attribute__((ext_vector_type(4)));
typedef unsigned short u16x8 __attribute__((ext_vector_type(8)));

__device__ inline unsigned short f2bf(float f) {
    union { float f; unsigned u; } x; x.f = f;
    unsigned u = x.u;
    unsigned r = (u + 0x7fffu + ((u >> 16) & 1u)) >> 16;  // RNE
    return (unsigned short)r;
}

__device__ inline void gload_lds16(const void* g, void* l) {
    __builtin_amdgcn_global_load_lds(
        (const __attribute__((address_space(1))) unsigned int*)g,
        (__attribute__((address_space(3))) unsigned int*)l, 16, 0, 0);
}

__device__ inline int div60(int v) { return (v * 17477) >> 20; }  // exact for 0<=v<3840

// ---- kernel 1 (fused prep): f32->bf16 convert (padded), vm + partial sum, warped centers ----
__global__ __launch_bounds__(256) void dl_prep_kernel(
    const float* __restrict__ desc, const float* __restrict__ wdesc,
    const float* __restrict__ homog, const float* __restrict__ mask,
    unsigned short* __restrict__ descb, unsigned short* __restrict__ wdescb,
    float* __restrict__ vm, float* __restrict__ vpart, float2* __restrict__ wcent)
{
    const int bid = blockIdx.x;
    const int tid = threadIdx.x;

    if (bid < CVT_BLOCKS) {
        int t = bid * 256 + tid;
        int brow = t >> 3;
        int col = (t & 7) * 8;
        int b = brow / MPAD;
        int row = brow - b * MPAD;
        u16x8 oa = (u16x8)0, ob = (u16x8)0;
        if (row < NCELL) {
            size_t src = ((size_t)(b * NCELL + row)) * DD + col;
            float4 a0 = *(const float4*)(desc + src);
            float4 a1 = *(const float4*)(desc + src + 4);
            float4 b0 = *(const float4*)(wdesc + src);
            float4 b1 = *(const float4*)(wdesc + src + 4);
            oa[0] = f2bf(a0.x); oa[1] = f2bf(a0.y); oa[2] = f2bf(a0.z); oa[3] = f2bf(a0.w);
            oa[4] = f2bf(a1.x); oa[5] = f2bf(a1.y); oa[6] = f2bf(a1.z); oa[7] = f2bf(a1.w);
            ob[0] = f2bf(b0.x); ob[1] = f2bf(b0.y); ob[2] = f2bf(b0.z); ob[3] = f2bf(b0.w);
            ob[4] = f2bf(b1.x); ob[5] = f2bf(b1.y); ob[6] = f2bf(b1.z); ob[7] = f2bf(b1.w);
        }
        size_t dst = (size_t)brow * DD + col;
        *(u16x8*)(descb + dst) = oa;
        *(u16x8*)(wdescb + dst) = ob;
    } else if (bid < CVT_BLOCKS + VM_BLOCKS) {
        int vb = bid - CVT_BLOCKS;
        int cell = vb * 256 + tid;
        float v = 0.f;
        if (cell < NBC) {
            int b = cell / NCELL;
            int rem = cell % NCELL;
            int k = rem / WCC, l = rem % WCC;
            const float* p = mask + (size_t)b * IMG * IMG + (size_t)(k * 8) * IMG + l * 8;
            float prod = 1.f;
#pragma unroll
            for (int dy = 0; dy < 8; ++dy) {
                float4 a0 = *(const float4*)(p + (size_t)dy * IMG);
                float4 a1 = *(const float4*)(p + (size_t)dy * IMG + 4);
                prod *= a0.x * a0.y * a0.z * a0.w * a1.x * a1.y * a1.z * a1.w;
            }
            vm[cell] = prod;
            v = prod;
        }
#pragma unroll
        for (int off = 32; off > 0; off >>= 1) v += __shfl_xor(v, off);
        __shared__ float sp[4];
        if ((tid & 63) == 0) sp[tid >> 6] = v;
        __syncthreads();
        if (tid == 0) vpart[vb] = sp[0] + sp[1] + sp[2] + sp[3];
    } else {
        int t = (bid - CVT_BLOCKS - VM_BLOCKS) * 256 + tid;   // 0 .. 15359
        int b = t / MPAD;
        int r = t - b * MPAD;
        float2 o;
        if (r < NCELL) {
            int i = div60(r);
            int j = r - i * WCC;
            const float* H = homog + b * 9;
            float x = (float)(j * 8 + 4), y = (float)(i * 8 + 4);
            float X2 = H[6] * x + H[7] * y + H[8];
            o.x = (H[3] * x + H[4] * y + H[5]) / X2;   // wy
            o.y = (H[0] * x + H[1] * y + H[2]) / X2;   // wx
        } else {
            o.x = 1e9f; o.y = 1e9f;                    // pad rows: s = 0, simple path
        }
        wcent[t] = o;
    }
}

// ---- kernel 2: 128x128-tile GEMM with fused max-form loss epilogue ----
__global__ __launch_bounds__(256, 3) void dl_gemm_loss_kernel(
    const unsigned short* __restrict__ descb, const unsigned short* __restrict__ wdescb,
    const float* __restrict__ vm, const float2* __restrict__ wcent,
    float* __restrict__ gpart)
{
    __shared__ unsigned char sA[128 * 128];   // 128 rows x 64 bf16, XOR-swizzled
    __shared__ unsigned char sB[128 * 128];
    __shared__ float2 swc[128];
    __shared__ float swave[4];

    const int b = blockIdx.z;
    const int m0 = blockIdx.x * 128;
    const int n0 = blockIdx.y * 128;
    const int tid = threadIdx.x;
    const int lane = tid & 63;
    const int wv = tid >> 6;                  // 0..3

    const unsigned char* gA = (const unsigned char*)(descb + (size_t)b * MPAD * DD) + (size_t)m0 * 128;
    const unsigned char* gB = (const unsigned char*)(wdescb + (size_t)b * MPAD * DD) + (size_t)n0 * 128;

    // stage tiles: LDS dest linear, swizzle via pre-swizzled global source (m173)
    {
        const int swz = ((lane & 7) ^ (lane >> 3)) << 4;
        const int lrow = lane >> 3;
#pragma unroll
        for (int t = 0; t < 4; ++t) {
            int row = wv * 32 + t * 8 + lrow;
            gload_lds16(gA + (size_t)row * 128 + swz, sA + wv * 4096 + t * 1024);
            gload_lds16(gB + (size_t)row * 128 + swz, sB + wv * 4096 + t * 1024);
        }
    }
    if (tid < 128) swc[tid] = wcent[b * MPAD + m0 + tid];

    const int wr = wv >> 1, wc = wv & 1;      // wave -> 64x64 subtile
    const int frow = lane & 15;
    const int kg = (lane >> 4) * 16;

    // ---- pre-barrier independent work (hides under staging vmcnt) ----
    float cyv[4], cxv[4], vmv[4];
#pragma unroll
    for (int fj = 0; fj < 4; ++fj) {
        int col = n0 + wc * 64 + fj * 16 + frow;
        int k = div60(col);
        int l = col - k * WCC;
        cyv[fj] = (float)(k * 8 + 4);
        cxv[fj] = (float)(l * 8 + 4);
        vmv[fj] = (col < NCELL) ? vm[b * NCELL + col] : 0.f;
    }
    // wave-uniform s-possibility test: row wy min/max (from global, not LDS)
    float wyl = wcent[b * MPAD + m0 + wr * 64 + lane].x;
    float wlo = wyl, whi = wyl;
#pragma unroll
    for (int off = 32; off > 0; off >>= 1) {
        wlo = fminf(wlo, __shfl_xor(wlo, off));
        whi = fmaxf(whi, __shfl_xor(whi, off));
    }
    int c0 = n0 + wc * 64;
    float cy0 = (float)(div60(c0) * 8 + 4) - 7.5f;
    float cy1 = (float)(div60(c0 + 63) * 8 + 4) + 7.5f;
    bool full = (whi >= cy0) && (wlo <= cy1);

    __syncthreads();

    f32x4 acc[4][4];
#pragma unroll
    for (int i2 = 0; i2 < 4; ++i2)
#pragma unroll
        for (int j2 = 0; j2 < 4; ++j2)
            acc[i2][j2] = (f32x4)(0.f);

#pragma unroll
    for (int kk = 0; kk < 2; ++kk) {
        int kbyte = kk * 64 + kg;
        bf16x8 afr[4], bfr[4];
#pragma unroll
        for (int f = 0; f < 4; ++f) {
            int ra = wr * 64 + f * 16 + frow;
            afr[f] = *(const bf16x8*)(sA + ra * 128 + (kbyte ^ ((ra & 7) << 4)));
            int rb = wc * 64 + f * 16 + frow;
            bfr[f] = *(const bf16x8*)(sB + rb * 128 + (kbyte ^ ((rb & 7) << 4)));
        }
#pragma unroll
        for (int fi = 0; fi < 4; ++fi)
#pragma unroll
            for (int fj = 0; fj < 4; ++fj)
                acc[fi][fj] = __builtin_amdgcn_mfma_f32_16x16x32_bf16(
                    afr[fi], bfr[fj], acc[fi][fj], 0, 0, 0);
    }

    // ---- max-form epilogue: accumulate vm*max(dot,0.2); global -0.2 correction in final ----
    // s=1 elements accumulate vm*(250*relu(1-dot)+0.2) so the same correction applies.
    float partial = 0.f;
    if (full) {
#pragma unroll
        for (int fi = 0; fi < 4; ++fi) {
#pragma unroll
            for (int q = 0; q < 4; ++q) {
                float2 w2 = swc[wr * 64 + fi * 16 + (lane >> 4) * 4 + q];
#pragma unroll
                for (int fj = 0; fj < 4; ++fj) {
                    float dot = acc[fi][fj][q];
                    float ddy = cyv[fj] - w2.x;
                    float ddx = cxv[fj] - w2.y;
                    float d2 = ddy * ddy + ddx * ddx;
                    float pos = 250.f * fmaxf(1.f - dot, 0.f) + 0.2f;
                    float neg = fmaxf(dot, 0.2f);
                    partial += vmv[fj] * ((d2 <= 56.25f) ? pos : neg);
                }
            }
        }
    } else {
#pragma unroll
        for (int fj = 0; fj < 4; ++fj) {
            float cs = 0.f;
#pragma unroll
            for (int fi = 0; fi < 4; ++fi)
#pragma unroll
                for (int q = 0; q < 4; ++q)
                    cs += fmaxf(acc[fi][fj][q], 0.2f);
            partial = fmaf(vmv[fj], cs, partial);
        }
    }

#pragma unroll
    for (int off = 32; off > 0; off >>= 1) partial += __shfl_xor(partial, off);
    if (lane == 0) swave[wv] = partial;
    __syncthreads();
    if (tid == 0)
        gpart[blockIdx.x + NT2 * (blockIdx.y + NT2 * b)] =
            swave[0] + swave[1] + swave[2] + swave[3];
}

// ---- kernel 3: final reduction -> scalar (applies the -0.2 max-form correction) ----
__global__ __launch_bounds__(256) void dl_final_kernel(
    const float* __restrict__ vpart, const float* __restrict__ gpart,
    float* __restrict__ out)
{
    int tid = threadIdx.x;
    float ls = 0.f, vs = 0.f;
    for (int i = tid; i < GEMM_BLOCKS; i += 256) ls += gpart[i];
    for (int i = tid; i < VM_BLOCKS; i += 256) vs += vpart[i];
#pragma unroll
    for (int off = 32; off > 0; off >>= 1) {
        ls += __shfl_xor(ls, off);
        vs += __shfl_xor(vs, off);
    }
    __shared__ float sl[4], sv[4];
    if ((tid & 63) == 0) { sl[tid >> 6] = ls; sv[tid >> 6] = vs; }
    __syncthreads();
    if (tid == 0) {
        float L = sl[0] + sl[1] + sl[2] + sl[3];
        float V = sv[0] + sv[1] + sv[2] + sv[3];
        L -= 0.2f * (float)MPAD * V;          // max-form global correction (768*V)
        out[0] = L / (V * (float)NCELL);
    }
}

extern "C" void kernel_launch(void* const* d_in, const int* in_sizes, int n_in,
                              void* d_out, int out_size, void* d_ws, size_t ws_size,
                              hipStream_t stream) {
    const float* desc  = (const float*)d_in[0];
    const float* wdesc = (const float*)d_in[1];
    const float* homog = (const float*)d_in[2];
    const float* mask  = (const float*)d_in[3];
    float* out = (float*)d_out;
    float* wsf = (float*)d_ws;

    // workspace layout (floats); every slot fully overwritten each call
    float* vpart = wsf;                           // [57]
    float* vm    = wsf + 64;                      // [14400]
    float* gpart = wsf + 64 + NBC;                // [3600] -> ends at 18064
    float2* wcent = (float2*)(wsf + 18064);       // [4*3840] float2 (8B aligned)
    unsigned short* descb  = (unsigned short*)(wsf + 49408);   // 256B-aligned
    unsigned short* wdescb = descb + (size_t)4 * MPAD * DD;

    hipLaunchKernelGGL(dl_prep_kernel, dim3(PREP_BLOCKS), dim3(256), 0, stream,
                       desc, wdesc, homog, mask, descb, wdescb, vm, vpart, wcent);
    hipLaunchKernelGGL(dl_gemm_loss_kernel, dim3(NT2, NT2, 4), dim3(256), 0, stream,
                       descb, wdescb, vm, wcent, gpart);
    hipLaunchKernelGGL(dl_final_kernel, dim3(1), dim3(256), 0, stream,
                       vpart, gpart, out);
}